// Round 7
// baseline (1505.893 us; speedup 1.0000x reference)
//
#include <hip/hip_runtime.h>
#include <cstdint>

#define T_STEPS 128
#define BATCH   1024
#define D_INPUT 96
#define H_DIM   128
#define NWIN    163   // 121 full 7-frame windows + 6 prefix partials + 36 clipped partials
#define BD      (BATCH * D_INPUT)   // 98304 floats per time frame

// (t, s) -> widx, or -1 when the reference window is empty (cur1 == +0)
__device__ __forceinline__ int widx_for(int t, int s) {
    if (t >= 49) return t - 49 + 7 * s;                 // slide regime: full windows
    if (s == 0)  return 121 + min(5, t);                // [0, min(5,t)]
    const int st = 7 * s - 1;
    if (t < st) return -1;
    const int len = min(7, t - st + 1);
    return (len == 7) ? st : (127 + (s - 1) * 6 + (len - 1));
}

// ---------------------------------------------------------------------------
// kT: one-shot weight reshapes.
//   blocks 0..47  : Win (128x96)  -> WinT (96x128)
//   blocks 48..111: Wh0 (128x128) -> Wh0P packed per (j, lane=i-pair l):
//     Wh0P[(j*64+l)*4 + {0,1,2,3}] = { Wh0[2l][2j], Wh0[2l+1][2j],
//                                      Wh0[2l][2j+1], Wh0[2l+1][2j+1] }
//   kB's lane (i-pair) fetches all 4 weights for h-pair j as ONE perfectly
//   coalesced float4 (64 lanes x 16 B = 1 KB line, L2-resident table).
// ---------------------------------------------------------------------------
__global__ __launch_bounds__(256) void kT_wint(const float* __restrict__ Win,
                                               const float* __restrict__ Wh0,
                                               float* __restrict__ WinT,
                                               float* __restrict__ Wh0P) {
    const int tid = threadIdx.x;
    if (blockIdx.x < 48) {
        const int e = blockIdx.x * 256 + tid;           // < 128*96
        const int h = e / D_INPUT, d = e % D_INPUT;
        WinT[d * H_DIM + h] = Win[e];
    } else {
        const int e = (blockIdx.x - 48) * 256 + tid;    // < 64*64*4 = 16384
        const int f = e & 3, l = (e >> 2) & 63, j = e >> 8;
        const int i = 2 * l + (f & 1);
        const int h = 2 * j + (f >> 1);
        Wh0P[e] = Wh0[i * H_DIM + h];
    }
}

// ---------------------------------------------------------------------------
// kA0: one streaming pass over x. Thread <-> (b,d); 7-frame ring in registers
// (t-loop fully unrolled -> all ring indices compile-time -> no scratch).
// Emits every window sum with the EXACT ascending-frame __fadd_rn chain.
// UNCHANGED.
// ---------------------------------------------------------------------------
__global__ __launch_bounds__(256) void kA0_winsum(const float* __restrict__ x,
                                                  float* __restrict__ WS) {
    const int flat = blockIdx.x * 256 + threadIdx.x;    // b*96 + d
    float* wsp = WS + flat;
    float r[7];
#pragma unroll
    for (int t = 0; t < T_STEPS; ++t) {
        r[t % 7] = x[(size_t)t * BD + flat];
        if (t <= 5) {                                   // s0 prefix, len = t+1
            float s = r[0];
#pragma unroll
            for (int k = 1; k <= t; ++k) s = __fadd_rn(s, r[k % 7]);
            wsp[(size_t)(121 + t) * BD] = s;
        }
        if (t >= 6 && t <= 126) {                       // full window w = t-6
            const int w = t - 6;
            float s = r[w % 7];
#pragma unroll
            for (int k = 1; k < 7; ++k) s = __fadd_rn(s, r[(w + k) % 7]);
            wsp[(size_t)w * BD] = s;
        }
        if (t >= 6 && t <= 46) {                        // grow partial (<=1 per t)
            const int sv = (t + 1) / 7;
            if (sv >= 1 && 7 * sv >= t - 4 && 7 * sv <= t + 1) {
                const int start = 7 * sv - 1;
                const int len = t - start + 1;          // 1..6 by construction
                float s = r[start % 7];
#pragma unroll
                for (int k = 1; k < len; ++k) s = __fadd_rn(s, r[(start + k) % 7]);
                wsp[(size_t)(127 + (sv - 1) * 6 + (len - 1)) * BD] = s;
            }
        }
    }
}

// ---------------------------------------------------------------------------
// kA1 (r6 version, verified): 64-b tile, lane = (h-quad q, b-octet).
// CUR1 bit-identical (ascending-d single-acc fma chain). UNCHANGED.
// ---------------------------------------------------------------------------
__global__ __launch_bounds__(256) void kA_wincur(const float* __restrict__ WS,
                                                 const float* __restrict__ WinT,
                                                 float* __restrict__ CUR1) {
    __shared__ float xs[D_INPUT * 64];                  // 24 KB, xs[d*64 + (bq^(d&24))]
    __shared__ float wq[D_INPUT * H_DIM];               // 48 KB, pair-split per row
    const int widx = blockIdx.x;
    const int b0   = blockIdx.y * 64;
    const int tid  = threadIdx.x;

    {
        const float2* WinT2 = (const float2*)WinT;
        for (int e2 = tid; e2 < D_INPUT * 64; e2 += 256) {
            const int p = e2 & 63, d = e2 >> 6;
            *(float2*)&wq[d * 128 + ((p & 1) << 6) + ((p >> 1) << 1)] = WinT2[e2];
        }
    }
    for (int e = tid; e < D_INPUT * 64; e += 256) {
        const int d = e % 96, bq = e / 96;
        xs[d * 64 + (bq ^ (d & 24))] =
            WS[(size_t)widx * BD + (size_t)(b0 + bq) * 96 + d];
    }
    __syncthreads();

    const int q  = tid & 31;                            // h-quad (4 h's)
    const int g  = (tid >> 5) & 1;
    const int w  = tid >> 6;
    const int ob = (w << 1) | g;                        // b-octet 0..7

    float acc[8][4];
#pragma unroll
    for (int r = 0; r < 8; ++r)
#pragma unroll
        for (int hh = 0; hh < 4; ++hh) acc[r][hh] = 0.f;

#pragma unroll 4
    for (int d = 0; d < D_INPUT; ++d) {
        const float2 wp0 = *(const float2*)&wq[d * 128 + 2 * q];       // h=4q,4q+1
        const float2 wp1 = *(const float2*)&wq[d * 128 + 64 + 2 * q];  // h=4q+2,4q+3
        const int xb = d * 64 + ((ob * 8) ^ (d & 24));
        const float4 xv0 = *(const float4*)&xs[xb];
        const float4 xv1 = *(const float4*)&xs[xb + 4];
        const float xv[8] = {xv0.x,xv0.y,xv0.z,xv0.w, xv1.x,xv1.y,xv1.z,xv1.w};
#pragma unroll
        for (int r = 0; r < 8; ++r) {
            acc[r][0] = __fmaf_rn(xv[r], wp0.x, acc[r][0]);
            acc[r][1] = __fmaf_rn(xv[r], wp0.y, acc[r][1]);
            acc[r][2] = __fmaf_rn(xv[r], wp1.x, acc[r][2]);
            acc[r][3] = __fmaf_rn(xv[r], wp1.y, acc[r][3]);
        }
    }
    float* op = CUR1 + ((size_t)widx * BATCH + b0 + ob * 8) * H_DIM + 4 * q;
#pragma unroll
    for (int r = 0; r < 8; ++r) {
        float4 o; o.x = acc[r][0]; o.y = acc[r][1]; o.z = acc[r][2]; o.w = acc[r][3];
        *(float4*)(op + (size_t)r * H_DIM) = o;
    }
}

// ---------------------------------------------------------------------------
// kB (round-7 rewrite): ZERO-LDS spike exchange via v_readlane.
// Wave = 8 b's, all 128 h (mem1: lane = h-pair) and all 128 i (cur2: lane =
// i-pair). The wave is SELF-CONTAINED: lane j's mem1 registers hold exactly
// the spike bits cur2 needs for h-pair j. Each lane packs its 8 se + 8 so
// bools into a 16-bit mask; per j, ONE v_readlane (imm lane index, full
// unroll) hands the mask to the scalar unit; the (M>>k)&1 ? 1:0 selects are
// wave-uniform -> SALU-only (co-issued, free); fma consumes the uniform
// se/so as its SGPR operand. Per j: 1 coalesced b128 weight load (16 B/lane,
// Wh0P, L2-hot) + 1 readlane + 32 fma. No LDS anywhere, no barriers.
// Bit-exactness: fma chain per (b,i) is ascending h with single accumulator
// and identical {0,1} multiplicands (fma(0,w,c)==c, fma(1,w,c)==add_rn);
// mem1/mem2/spike arithmetic verbatim. Linear Wout tail stays relaxed
// (64-lane tree reduce). __launch_bounds__(256,3): VGPR cap 170 — generous
// anti-spill margin (r2 lesson); est. live state ~110 regs.
// ---------------------------------------------------------------------------
__global__ __launch_bounds__(256, 3) void kB_snn(const float* __restrict__ CUR1,
                                                 const float* __restrict__ Wh0P,
                                                 const float* __restrict__ Wout,
                                                 const float* __restrict__ vxp,
                                                 const float* __restrict__ vyp,
                                                 float* __restrict__ out) {
    const int tid  = threadIdx.x;
    const int w    = tid >> 6, lane = tid & 63;
    const int t    = blockIdx.y;
    const int i0   = lane << 1;                 // mem1: h-pair; cur2: i-pair
    const int b0   = (blockIdx.x << 5) + (w << 3);   // 8 consecutive b per wave
    const float vx = vxp[0], vy = vyp[0];
    const float wex0 = Wout[i0],         wex1 = Wout[i0 + 1];
    const float wey0 = Wout[H_DIM + i0], wey1 = Wout[H_DIM + i0 + 1];

    float m1a[8], m1b[8];                       // h = 2*lane / 2*lane+1, x 8 b
    bool  s1a[8], s1b[8];
    float m2[8][2], po0[8], po1[8];
    bool  s2[8][2];
#pragma unroll
    for (int k = 0; k < 8; ++k) {
        m1a[k] = 0.f; m1b[k] = 0.f; s1a[k] = false; s1b[k] = false;
        m2[k][0] = 0.f; m2[k][1] = 0.f; s2[k][0] = false; s2[k][1] = false;
        po0[k] = 0.f; po1[k] = 0.f;
    }

#pragma unroll 1
    for (int s = 0; s < 7; ++s) {
        // ---- load cur1 for this step (coalesced float2 per b) --------------
        const int wi = widx_for(t, s);
        float c1a[8], c1b[8];
#pragma unroll
        for (int k = 0; k < 8; ++k) {
            c1a[k] = 0.f; c1b[k] = 0.f;
            if (wi >= 0) {
                const float2 v = *(const float2*)
                    &CUR1[((size_t)wi * BATCH + b0 + k) * H_DIM + i0];
                c1a[k] = v.x; c1b[k] = v.y;
            }
        }

        // ---- mem1 update + pack spike bits (exact values) ------------------
        uint32_t mk = 0u;                       // bits 0..7 = se(h=2*lane), 8..15 = so
#pragma unroll
        for (int k = 0; k < 8; ++k) {
            m1a[k] = s1a[k] ? 0.f : __fadd_rn(__fmul_rn(0.9f, m1a[k]), c1a[k]);
            m1b[k] = s1b[k] ? 0.f : __fadd_rn(__fmul_rn(0.9f, m1b[k]), c1b[k]);
            s1a[k] = m1a[k] > 0.5f; s1b[k] = m1b[k] > 0.5f;
            mk |= (s1a[k] ? (1u << k) : 0u) | (s1b[k] ? (0x100u << k) : 0u);
        }

        // ---- dense cur2: ascending h; spikes via readlane (no LDS) ---------
        float c2[8][2];
#pragma unroll
        for (int k = 0; k < 8; ++k) { c2[k][0] = 0.f; c2[k][1] = 0.f; }

#pragma unroll
        for (int j = 0; j < 64; ++j) {
            const float4 wv = *(const float4*)&Wh0P[((size_t)(j * 64 + lane)) * 4];
            const uint32_t M = (uint32_t)__builtin_amdgcn_readlane((int)mk, j);
#pragma unroll
            for (int k = 0; k < 8; ++k) {
                const float se = (M & (1u     << k)) ? 1.0f : 0.0f;  // uniform -> SGPR
                const float so = (M & (0x100u << k)) ? 1.0f : 0.0f;
                c2[k][0] = __fmaf_rn(se, wv.x, c2[k][0]);   // h = 2j,   i = i0
                c2[k][1] = __fmaf_rn(se, wv.y, c2[k][1]);   // h = 2j,   i = i0+1
                c2[k][0] = __fmaf_rn(so, wv.z, c2[k][0]);   // h = 2j+1, i = i0
                c2[k][1] = __fmaf_rn(so, wv.w, c2[k][1]);   // h = 2j+1, i = i0+1
            }
        }

        // ---- mem2 + spikes (exact) and linear output tail (relaxed) --------
#pragma unroll
        for (int k = 0; k < 8; ++k) {
            m2[k][0] = s2[k][0] ? 0.f : __fadd_rn(__fmul_rn(0.9f, m2[k][0]), c2[k][0]);
            m2[k][1] = s2[k][1] ? 0.f : __fadd_rn(__fmul_rn(0.9f, m2[k][1]), c2[k][1]);
            s2[k][0] = m2[k][0] > 0.5f; s2[k][1] = m2[k][1] > 0.5f;
            const float p0 = (s2[k][0] ? wex0 : 0.f) + (s2[k][1] ? wex1 : 0.f);
            const float p1 = (s2[k][0] ? wey0 : 0.f) + (s2[k][1] ? wey1 : 0.f);
            po0[k] = __fmaf_rn(0.9f, po0[k], p0);   // mem_out linear: order-safe
            po1[k] = __fmaf_rn(0.9f, po1[k], p1);
        }
    }

    // ---- reduce per-lane (2-i) partials over 64 lanes (128 i), write -------
#pragma unroll
    for (int k = 0; k < 8; ++k) {
        float r0 = po0[k], r1 = po1[k];
#pragma unroll
        for (int off = 32; off > 0; off >>= 1) {
            r0 += __shfl_xor(r0, off);
            r1 += __shfl_xor(r1, off);
        }
        if (lane == 0) {
            float2 o;
            o.x = __fmul_rn(r0, vx);
            o.y = __fmul_rn(r1, vy);
            *(float2*)(out + ((size_t)t * BATCH + b0 + k) * 2) = o;
        }
    }
}

// ---------------------------------------------------------------------------
extern "C" void kernel_launch(void* const* d_in, const int* in_sizes, int n_in,
                              void* d_out, int out_size, void* d_ws, size_t ws_size,
                              hipStream_t stream) {
    const float* x    = (const float*)d_in[0];   // (128,1024,96)
    const float* Win  = (const float*)d_in[1];   // (128,96)
    const float* Wh0  = (const float*)d_in[2];   // (128,128)
    const float* Wout = (const float*)d_in[3];   // (2,128)
    const float* vx   = (const float*)d_in[4];   // (1,)
    const float* vy   = (const float*)d_in[5];   // (1,)
    float* out  = (float*)d_out;                 // (128,1024,2)

    // workspace: CUR1 (85.5 MB) | WS (64.1 MB) | WinT (48 KB) | Wh0P (64 KB)
    float* CUR1 = (float*)d_ws;
    float* WS   = CUR1 + (size_t)NWIN * BATCH * H_DIM;
    float* WinT = WS   + (size_t)NWIN * BATCH * D_INPUT;
    float* Wh0P = WinT + (size_t)D_INPUT * H_DIM;

    kT_wint   <<<dim3(112),                 dim3(256), 0, stream>>>(Win, Wh0, WinT, Wh0P);
    kA0_winsum<<<dim3(BD / 256),            dim3(256), 0, stream>>>(x, WS);
    kA_wincur <<<dim3(NWIN, BATCH / 64),    dim3(256), 0, stream>>>(WS, WinT, CUR1);
    kB_snn    <<<dim3(BATCH / 32, T_STEPS), dim3(256), 0, stream>>>(CUR1, Wh0P, Wout, vx, vy, out);
}

// Round 8
// 826.055 us; speedup vs baseline: 1.8230x; 1.8230x over previous
//
#include <hip/hip_runtime.h>
#include <cstdint>

#define T_STEPS 128
#define BATCH   1024
#define D_INPUT 96
#define H_DIM   128
#define NWIN    163   // 121 full 7-frame windows + 6 prefix partials + 36 clipped partials
#define BD      (BATCH * D_INPUT)   // 98304 floats per time frame

// (t, s) -> widx, or -1 when the reference window is empty (cur1 == +0)
__device__ __forceinline__ int widx_for(int t, int s) {
    if (t >= 49) return t - 49 + 7 * s;                 // slide regime: full windows
    if (s == 0)  return 121 + min(5, t);                // [0, min(5,t)]
    const int st = 7 * s - 1;
    if (t < st) return -1;
    const int len = min(7, t - st + 1);
    return (len == 7) ? st : (127 + (s - 1) * 6 + (len - 1));
}

// ---------------------------------------------------------------------------
// kT: one-shot weight reshapes.
//   blocks 0..47  : Win (128x96)  -> WinT (96x128)
//   blocks 48..111: Wh0 (128x128) -> Wh0P packed per (j, lane=i-pair l):
//     Wh0P[(j*64+l)*4 + {0,1,2,3}] = { Wh0[2l][2j], Wh0[2l+1][2j],
//                                      Wh0[2l][2j+1], Wh0[2l+1][2j+1] }
// ---------------------------------------------------------------------------
__global__ __launch_bounds__(256) void kT_wint(const float* __restrict__ Win,
                                               const float* __restrict__ Wh0,
                                               float* __restrict__ WinT,
                                               float* __restrict__ Wh0P) {
    const int tid = threadIdx.x;
    if (blockIdx.x < 48) {
        const int e = blockIdx.x * 256 + tid;           // < 128*96
        const int h = e / D_INPUT, d = e % D_INPUT;
        WinT[d * H_DIM + h] = Win[e];
    } else {
        const int e = (blockIdx.x - 48) * 256 + tid;    // < 64*64*4 = 16384
        const int f = e & 3, l = (e >> 2) & 63, j = e >> 8;
        const int i = 2 * l + (f & 1);
        const int h = 2 * j + (f >> 1);
        Wh0P[e] = Wh0[i * H_DIM + h];
    }
}

// ---------------------------------------------------------------------------
// kA0: one streaming pass over x. Thread <-> (b,d); 7-frame ring in registers
// (t-loop fully unrolled -> all ring indices compile-time -> no scratch).
// Emits every window sum with the EXACT ascending-frame __fadd_rn chain.
// UNCHANGED.
// ---------------------------------------------------------------------------
__global__ __launch_bounds__(256) void kA0_winsum(const float* __restrict__ x,
                                                  float* __restrict__ WS) {
    const int flat = blockIdx.x * 256 + threadIdx.x;    // b*96 + d
    float* wsp = WS + flat;
    float r[7];
#pragma unroll
    for (int t = 0; t < T_STEPS; ++t) {
        r[t % 7] = x[(size_t)t * BD + flat];
        if (t <= 5) {                                   // s0 prefix, len = t+1
            float s = r[0];
#pragma unroll
            for (int k = 1; k <= t; ++k) s = __fadd_rn(s, r[k % 7]);
            wsp[(size_t)(121 + t) * BD] = s;
        }
        if (t >= 6 && t <= 126) {                       // full window w = t-6
            const int w = t - 6;
            float s = r[w % 7];
#pragma unroll
            for (int k = 1; k < 7; ++k) s = __fadd_rn(s, r[(w + k) % 7]);
            wsp[(size_t)w * BD] = s;
        }
        if (t >= 6 && t <= 46) {                        // grow partial (<=1 per t)
            const int sv = (t + 1) / 7;
            if (sv >= 1 && 7 * sv >= t - 4 && 7 * sv <= t + 1) {
                const int start = 7 * sv - 1;
                const int len = t - start + 1;          // 1..6 by construction
                float s = r[start % 7];
#pragma unroll
                for (int k = 1; k < len; ++k) s = __fadd_rn(s, r[(start + k) % 7]);
                wsp[(size_t)(127 + (sv - 1) * 6 + (len - 1)) * BD] = s;
            }
        }
    }
}

// ---------------------------------------------------------------------------
// kA1 (r6 version, verified): 64-b tile, lane = (h-quad q, b-octet).
// CUR1 bit-identical (ascending-d single-acc fma chain). UNCHANGED.
// ---------------------------------------------------------------------------
__global__ __launch_bounds__(256) void kA_wincur(const float* __restrict__ WS,
                                                 const float* __restrict__ WinT,
                                                 float* __restrict__ CUR1) {
    __shared__ float xs[D_INPUT * 64];                  // 24 KB, xs[d*64 + (bq^(d&24))]
    __shared__ float wq[D_INPUT * H_DIM];               // 48 KB, pair-split per row
    const int widx = blockIdx.x;
    const int b0   = blockIdx.y * 64;
    const int tid  = threadIdx.x;

    {
        const float2* WinT2 = (const float2*)WinT;
        for (int e2 = tid; e2 < D_INPUT * 64; e2 += 256) {
            const int p = e2 & 63, d = e2 >> 6;
            *(float2*)&wq[d * 128 + ((p & 1) << 6) + ((p >> 1) << 1)] = WinT2[e2];
        }
    }
    for (int e = tid; e < D_INPUT * 64; e += 256) {
        const int d = e % 96, bq = e / 96;
        xs[d * 64 + (bq ^ (d & 24))] =
            WS[(size_t)widx * BD + (size_t)(b0 + bq) * 96 + d];
    }
    __syncthreads();

    const int q  = tid & 31;                            // h-quad (4 h's)
    const int g  = (tid >> 5) & 1;
    const int w  = tid >> 6;
    const int ob = (w << 1) | g;                        // b-octet 0..7

    float acc[8][4];
#pragma unroll
    for (int r = 0; r < 8; ++r)
#pragma unroll
        for (int hh = 0; hh < 4; ++hh) acc[r][hh] = 0.f;

#pragma unroll 4
    for (int d = 0; d < D_INPUT; ++d) {
        const float2 wp0 = *(const float2*)&wq[d * 128 + 2 * q];       // h=4q,4q+1
        const float2 wp1 = *(const float2*)&wq[d * 128 + 64 + 2 * q];  // h=4q+2,4q+3
        const int xb = d * 64 + ((ob * 8) ^ (d & 24));
        const float4 xv0 = *(const float4*)&xs[xb];
        const float4 xv1 = *(const float4*)&xs[xb + 4];
        const float xv[8] = {xv0.x,xv0.y,xv0.z,xv0.w, xv1.x,xv1.y,xv1.z,xv1.w};
#pragma unroll
        for (int r = 0; r < 8; ++r) {
            acc[r][0] = __fmaf_rn(xv[r], wp0.x, acc[r][0]);
            acc[r][1] = __fmaf_rn(xv[r], wp0.y, acc[r][1]);
            acc[r][2] = __fmaf_rn(xv[r], wp1.x, acc[r][2]);
            acc[r][3] = __fmaf_rn(xv[r], wp1.y, acc[r][3]);
        }
    }
    float* op = CUR1 + ((size_t)widx * BATCH + b0 + ob * 8) * H_DIM + 4 * q;
#pragma unroll
    for (int r = 0; r < 8; ++r) {
        float4 o; o.x = acc[r][0]; o.y = acc[r][1]; o.z = acc[r][2]; o.w = acc[r][3];
        *(float4*)(op + (size_t)r * H_DIM) = o;
    }
}

// ---------------------------------------------------------------------------
// kB (round-8): readlane spike exchange (r7, verified correct) + LDS-resident
// weight table (fixes r7's two failures):
//   1) SPILL: r7's fully-unrolled j-loop hoisted ~64 in-flight float4 VMEM
//      loads past the (256,3) cap -> 2 GB scratch traffic. Now the j-loop is
//      unrolled x4 only (<=16 transient regs) and weights are ds_read_b128
//      (compiler won't pile up lgkm-counted loads the same way).
//   2) WEIGHT RE-STREAM: 8-b waves re-read the 64 KB table per step from
//      L1/L2 (~7.3 GB L2 demand ~= 213 µs). Now each block stages the table
//      into LDS once; per-lane contiguous 16-B reads are conflict-free.
// LDS pipe/CU: 16 waves x 64j x 7s x 12cyc ~= 86k cyc < VALU ~114k -> VALU-
// bound. No barriers in the s-loop (spikes never touch LDS: readlane +
// wave-uniform SALU selects feeding fma SGPR operands).
// Bit-exact: identical fma chain/operands as r7 (which passed); LDS copy is
// an identity on weight values. __launch_bounds__(512,2): proven <=124 VGPR
// regime; 64 KB LDS -> 2 blocks/CU -> 16 waves/CU.
// ---------------------------------------------------------------------------
__global__ __launch_bounds__(512, 2) void kB_snn(const float* __restrict__ CUR1,
                                                 const float* __restrict__ Wh0P,
                                                 const float* __restrict__ Wout,
                                                 const float* __restrict__ vxp,
                                                 const float* __restrict__ vyp,
                                                 float* __restrict__ out) {
    __shared__ float4 lw[64 * 64];                     // 64 KB: lw[j*64 + lane]
    const int tid  = threadIdx.x;

    // stage weight table once (coalesced float4, 8 per thread)
    {
        const float4* src = (const float4*)Wh0P;
        for (int e = tid; e < 4096; e += 512) lw[e] = src[e];
    }
    __syncthreads();

    const int w    = tid >> 6, lane = tid & 63;
    const int t    = blockIdx.y;
    const int i0   = lane << 1;                 // mem1: h-pair; cur2: i-pair
    const int b0   = (blockIdx.x << 6) + (w << 3);   // 8 consecutive b per wave
    const float vx = vxp[0], vy = vyp[0];
    const float wex0 = Wout[i0],         wex1 = Wout[i0 + 1];
    const float wey0 = Wout[H_DIM + i0], wey1 = Wout[H_DIM + i0 + 1];

    float m1a[8], m1b[8];                       // h = 2*lane / 2*lane+1, x 8 b
    bool  s1a[8], s1b[8];
    float m2[8][2], po0[8], po1[8];
    bool  s2[8][2];
#pragma unroll
    for (int k = 0; k < 8; ++k) {
        m1a[k] = 0.f; m1b[k] = 0.f; s1a[k] = false; s1b[k] = false;
        m2[k][0] = 0.f; m2[k][1] = 0.f; s2[k][0] = false; s2[k][1] = false;
        po0[k] = 0.f; po1[k] = 0.f;
    }

#pragma unroll 1
    for (int s = 0; s < 7; ++s) {
        // ---- load cur1 for this step (coalesced float2 per b) --------------
        const int wi = widx_for(t, s);
        float c1a[8], c1b[8];
#pragma unroll
        for (int k = 0; k < 8; ++k) {
            c1a[k] = 0.f; c1b[k] = 0.f;
            if (wi >= 0) {
                const float2 v = *(const float2*)
                    &CUR1[((size_t)wi * BATCH + b0 + k) * H_DIM + i0];
                c1a[k] = v.x; c1b[k] = v.y;
            }
        }

        // ---- mem1 update + pack spike bits (exact values) ------------------
        uint32_t mk = 0u;                       // bits 0..7 = se(h=2*lane), 8..15 = so
#pragma unroll
        for (int k = 0; k < 8; ++k) {
            m1a[k] = s1a[k] ? 0.f : __fadd_rn(__fmul_rn(0.9f, m1a[k]), c1a[k]);
            m1b[k] = s1b[k] ? 0.f : __fadd_rn(__fmul_rn(0.9f, m1b[k]), c1b[k]);
            s1a[k] = m1a[k] > 0.5f; s1b[k] = m1b[k] > 0.5f;
            mk |= (s1a[k] ? (1u << k) : 0u) | (s1b[k] ? (0x100u << k) : 0u);
        }

        // ---- dense cur2: ascending h; spikes via readlane, weights via LDS -
        float c2[8][2];
#pragma unroll
        for (int k = 0; k < 8; ++k) { c2[k][0] = 0.f; c2[k][1] = 0.f; }

#pragma unroll 4
        for (int j = 0; j < 64; ++j) {
            const float4 wv = lw[j * 64 + lane];                 // ds_read_b128
            const uint32_t M = (uint32_t)__builtin_amdgcn_readlane((int)mk, j);
#pragma unroll
            for (int k = 0; k < 8; ++k) {
                const float se = (M & (1u     << k)) ? 1.0f : 0.0f;  // uniform -> SGPR
                const float so = (M & (0x100u << k)) ? 1.0f : 0.0f;
                c2[k][0] = __fmaf_rn(se, wv.x, c2[k][0]);   // h = 2j,   i = i0
                c2[k][1] = __fmaf_rn(se, wv.y, c2[k][1]);   // h = 2j,   i = i0+1
                c2[k][0] = __fmaf_rn(so, wv.z, c2[k][0]);   // h = 2j+1, i = i0
                c2[k][1] = __fmaf_rn(so, wv.w, c2[k][1]);   // h = 2j+1, i = i0+1
            }
        }

        // ---- mem2 + spikes (exact) and linear output tail (relaxed) --------
#pragma unroll
        for (int k = 0; k < 8; ++k) {
            m2[k][0] = s2[k][0] ? 0.f : __fadd_rn(__fmul_rn(0.9f, m2[k][0]), c2[k][0]);
            m2[k][1] = s2[k][1] ? 0.f : __fadd_rn(__fmul_rn(0.9f, m2[k][1]), c2[k][1]);
            s2[k][0] = m2[k][0] > 0.5f; s2[k][1] = m2[k][1] > 0.5f;
            const float p0 = (s2[k][0] ? wex0 : 0.f) + (s2[k][1] ? wex1 : 0.f);
            const float p1 = (s2[k][0] ? wey0 : 0.f) + (s2[k][1] ? wey1 : 0.f);
            po0[k] = __fmaf_rn(0.9f, po0[k], p0);   // mem_out linear: order-safe
            po1[k] = __fmaf_rn(0.9f, po1[k], p1);
        }
    }

    // ---- reduce per-lane (2-i) partials over 64 lanes (128 i), write -------
#pragma unroll
    for (int k = 0; k < 8; ++k) {
        float r0 = po0[k], r1 = po1[k];
#pragma unroll
        for (int off = 32; off > 0; off >>= 1) {
            r0 += __shfl_xor(r0, off);
            r1 += __shfl_xor(r1, off);
        }
        if (lane == 0) {
            float2 o;
            o.x = __fmul_rn(r0, vx);
            o.y = __fmul_rn(r1, vy);
            *(float2*)(out + ((size_t)t * BATCH + b0 + k) * 2) = o;
        }
    }
}

// ---------------------------------------------------------------------------
extern "C" void kernel_launch(void* const* d_in, const int* in_sizes, int n_in,
                              void* d_out, int out_size, void* d_ws, size_t ws_size,
                              hipStream_t stream) {
    const float* x    = (const float*)d_in[0];   // (128,1024,96)
    const float* Win  = (const float*)d_in[1];   // (128,96)
    const float* Wh0  = (const float*)d_in[2];   // (128,128)
    const float* Wout = (const float*)d_in[3];   // (2,128)
    const float* vx   = (const float*)d_in[4];   // (1,)
    const float* vy   = (const float*)d_in[5];   // (1,)
    float* out  = (float*)d_out;                 // (128,1024,2)

    // workspace: CUR1 (85.5 MB) | WS (64.1 MB) | WinT (48 KB) | Wh0P (64 KB)
    float* CUR1 = (float*)d_ws;
    float* WS   = CUR1 + (size_t)NWIN * BATCH * H_DIM;
    float* WinT = WS   + (size_t)NWIN * BATCH * D_INPUT;
    float* Wh0P = WinT + (size_t)D_INPUT * H_DIM;

    kT_wint   <<<dim3(112),                 dim3(256), 0, stream>>>(Win, Wh0, WinT, Wh0P);
    kA0_winsum<<<dim3(BD / 256),            dim3(256), 0, stream>>>(x, WS);
    kA_wincur <<<dim3(NWIN, BATCH / 64),    dim3(256), 0, stream>>>(WS, WinT, CUR1);
    kB_snn    <<<dim3(BATCH / 64, T_STEPS), dim3(512), 0, stream>>>(CUR1, Wh0P, Wout, vx, vy, out);
}

// Round 9
// 803.225 us; speedup vs baseline: 1.8748x; 1.0284x over previous
//
#include <hip/hip_runtime.h>
#include <cstdint>

#define T_STEPS 128
#define BATCH   1024
#define D_INPUT 96
#define H_DIM   128
#define NWIN    163   // 121 full 7-frame windows + 6 prefix partials + 36 clipped partials
#define BD      (BATCH * D_INPUT)   // 98304 floats per time frame

// (t, s) -> widx, or -1 when the reference window is empty (cur1 == +0)
__device__ __forceinline__ int widx_for(int t, int s) {
    if (t >= 49) return t - 49 + 7 * s;                 // slide regime: full windows
    if (s == 0)  return 121 + min(5, t);                // [0, min(5,t)]
    const int st = 7 * s - 1;
    if (t < st) return -1;
    const int len = min(7, t - st + 1);
    return (len == 7) ? st : (127 + (s - 1) * 6 + (len - 1));
}

// ---------------------------------------------------------------------------
// kT: one-shot weight reshapes.
//   blocks 0..47  : Win (128x96)  -> WinT (96x128)
//   blocks 48..111: Wh0 (128x128) -> Wh0P packed per (j, lane=i-pair l):
//     Wh0P[(j*64+l)*4 + {0,1,2,3}] = { Wh0[2l][2j], Wh0[2l+1][2j],
//                                      Wh0[2l][2j+1], Wh0[2l+1][2j+1] }
// ---------------------------------------------------------------------------
__global__ __launch_bounds__(256) void kT_wint(const float* __restrict__ Win,
                                               const float* __restrict__ Wh0,
                                               float* __restrict__ WinT,
                                               float* __restrict__ Wh0P) {
    const int tid = threadIdx.x;
    if (blockIdx.x < 48) {
        const int e = blockIdx.x * 256 + tid;           // < 128*96
        const int h = e / D_INPUT, d = e % D_INPUT;
        WinT[d * H_DIM + h] = Win[e];
    } else {
        const int e = (blockIdx.x - 48) * 256 + tid;    // < 64*64*4 = 16384
        const int f = e & 3, l = (e >> 2) & 63, j = e >> 8;
        const int i = 2 * l + (f & 1);
        const int h = 2 * j + (f >> 1);
        Wh0P[e] = Wh0[i * H_DIM + h];
    }
}

// ---------------------------------------------------------------------------
// kA0: one streaming pass over x. Thread <-> (b,d); 7-frame ring in registers
// (t-loop fully unrolled -> all ring indices compile-time -> no scratch).
// Emits every window sum with the EXACT ascending-frame __fadd_rn chain.
// UNCHANGED.
// ---------------------------------------------------------------------------
__global__ __launch_bounds__(256) void kA0_winsum(const float* __restrict__ x,
                                                  float* __restrict__ WS) {
    const int flat = blockIdx.x * 256 + threadIdx.x;    // b*96 + d
    float* wsp = WS + flat;
    float r[7];
#pragma unroll
    for (int t = 0; t < T_STEPS; ++t) {
        r[t % 7] = x[(size_t)t * BD + flat];
        if (t <= 5) {                                   // s0 prefix, len = t+1
            float s = r[0];
#pragma unroll
            for (int k = 1; k <= t; ++k) s = __fadd_rn(s, r[k % 7]);
            wsp[(size_t)(121 + t) * BD] = s;
        }
        if (t >= 6 && t <= 126) {                       // full window w = t-6
            const int w = t - 6;
            float s = r[w % 7];
#pragma unroll
            for (int k = 1; k < 7; ++k) s = __fadd_rn(s, r[(w + k) % 7]);
            wsp[(size_t)w * BD] = s;
        }
        if (t >= 6 && t <= 46) {                        // grow partial (<=1 per t)
            const int sv = (t + 1) / 7;
            if (sv >= 1 && 7 * sv >= t - 4 && 7 * sv <= t + 1) {
                const int start = 7 * sv - 1;
                const int len = t - start + 1;          // 1..6 by construction
                float s = r[start % 7];
#pragma unroll
                for (int k = 1; k < len; ++k) s = __fadd_rn(s, r[(start + k) % 7]);
                wsp[(size_t)(127 + (sv - 1) * 6 + (len - 1)) * BD] = s;
            }
        }
    }
}

// ---------------------------------------------------------------------------
// kA1 (r6 version, verified): 64-b tile, lane = (h-quad q, b-octet).
// CUR1 bit-identical (ascending-d single-acc fma chain). UNCHANGED.
// ---------------------------------------------------------------------------
__global__ __launch_bounds__(256) void kA_wincur(const float* __restrict__ WS,
                                                 const float* __restrict__ WinT,
                                                 float* __restrict__ CUR1) {
    __shared__ float xs[D_INPUT * 64];                  // 24 KB, xs[d*64 + (bq^(d&24))]
    __shared__ float wq[D_INPUT * H_DIM];               // 48 KB, pair-split per row
    const int widx = blockIdx.x;
    const int b0   = blockIdx.y * 64;
    const int tid  = threadIdx.x;

    {
        const float2* WinT2 = (const float2*)WinT;
        for (int e2 = tid; e2 < D_INPUT * 64; e2 += 256) {
            const int p = e2 & 63, d = e2 >> 6;
            *(float2*)&wq[d * 128 + ((p & 1) << 6) + ((p >> 1) << 1)] = WinT2[e2];
        }
    }
    for (int e = tid; e < D_INPUT * 64; e += 256) {
        const int d = e % 96, bq = e / 96;
        xs[d * 64 + (bq ^ (d & 24))] =
            WS[(size_t)widx * BD + (size_t)(b0 + bq) * 96 + d];
    }
    __syncthreads();

    const int q  = tid & 31;                            // h-quad (4 h's)
    const int g  = (tid >> 5) & 1;
    const int w  = tid >> 6;
    const int ob = (w << 1) | g;                        // b-octet 0..7

    float acc[8][4];
#pragma unroll
    for (int r = 0; r < 8; ++r)
#pragma unroll
        for (int hh = 0; hh < 4; ++hh) acc[r][hh] = 0.f;

#pragma unroll 4
    for (int d = 0; d < D_INPUT; ++d) {
        const float2 wp0 = *(const float2*)&wq[d * 128 + 2 * q];       // h=4q,4q+1
        const float2 wp1 = *(const float2*)&wq[d * 128 + 64 + 2 * q];  // h=4q+2,4q+3
        const int xb = d * 64 + ((ob * 8) ^ (d & 24));
        const float4 xv0 = *(const float4*)&xs[xb];
        const float4 xv1 = *(const float4*)&xs[xb + 4];
        const float xv[8] = {xv0.x,xv0.y,xv0.z,xv0.w, xv1.x,xv1.y,xv1.z,xv1.w};
#pragma unroll
        for (int r = 0; r < 8; ++r) {
            acc[r][0] = __fmaf_rn(xv[r], wp0.x, acc[r][0]);
            acc[r][1] = __fmaf_rn(xv[r], wp0.y, acc[r][1]);
            acc[r][2] = __fmaf_rn(xv[r], wp1.x, acc[r][2]);
            acc[r][3] = __fmaf_rn(xv[r], wp1.y, acc[r][3]);
        }
    }
    float* op = CUR1 + ((size_t)widx * BATCH + b0 + ob * 8) * H_DIM + 4 * q;
#pragma unroll
    for (int r = 0; r < 8; ++r) {
        float4 o; o.x = acc[r][0]; o.y = acc[r][1]; o.z = acc[r][2]; o.w = acc[r][3];
        *(float4*)(op + (size_t)r * H_DIM) = o;
    }
}

// ---------------------------------------------------------------------------
// kB (round-9): r8 body verbatim; ONLY the block shape changes.
// r8 counters: VGPR=60 (register file admits 32 waves/CU) but 512-thread
// blocks each carrying the 64 KB table capped residency at 16 waves/CU
// (Occupancy 39%). Now 1024-thread blocks (16 waves) SHARE one 64 KB table:
// 2 blocks/CU -> 32 waves/CU = 8 waves/SIMD (max). __launch_bounds__(1024,8)
// = VGPR cap 64 (current use 60, margin 4; body unchanged so regalloc
// pressure unchanged). Spill tripwire: WRITE_SIZE must stay ~1 KB.
// Single-variable experiment: if r8's VALUBusy=85% is real, bounded gain
// (~1.18x); if it's fallback-formula noise and the truth is latency-stall
// at 4 waves/SIMD, large gain. Readlane spike path, LDS weights, fma
// chain/operands: bit-identical to r8 (verified pass).
// ---------------------------------------------------------------------------
__global__ __launch_bounds__(1024, 8) void kB_snn(const float* __restrict__ CUR1,
                                                  const float* __restrict__ Wh0P,
                                                  const float* __restrict__ Wout,
                                                  const float* __restrict__ vxp,
                                                  const float* __restrict__ vyp,
                                                  float* __restrict__ out) {
    __shared__ float4 lw[64 * 64];                     // 64 KB: lw[j*64 + lane]
    const int tid  = threadIdx.x;

    // stage weight table once (coalesced float4, 4 per thread)
    {
        const float4* src = (const float4*)Wh0P;
        for (int e = tid; e < 4096; e += 1024) lw[e] = src[e];
    }
    __syncthreads();

    const int w    = tid >> 6, lane = tid & 63;        // w in [0,16)
    const int t    = blockIdx.y;
    const int i0   = lane << 1;                 // mem1: h-pair; cur2: i-pair
    const int b0   = (blockIdx.x << 7) + (w << 3);   // 8 consecutive b per wave
    const float vx = vxp[0], vy = vyp[0];
    const float wex0 = Wout[i0],         wex1 = Wout[i0 + 1];
    const float wey0 = Wout[H_DIM + i0], wey1 = Wout[H_DIM + i0 + 1];

    float m1a[8], m1b[8];                       // h = 2*lane / 2*lane+1, x 8 b
    bool  s1a[8], s1b[8];
    float m2[8][2], po0[8], po1[8];
    bool  s2[8][2];
#pragma unroll
    for (int k = 0; k < 8; ++k) {
        m1a[k] = 0.f; m1b[k] = 0.f; s1a[k] = false; s1b[k] = false;
        m2[k][0] = 0.f; m2[k][1] = 0.f; s2[k][0] = false; s2[k][1] = false;
        po0[k] = 0.f; po1[k] = 0.f;
    }

#pragma unroll 1
    for (int s = 0; s < 7; ++s) {
        // ---- load cur1 for this step (coalesced float2 per b) --------------
        const int wi = widx_for(t, s);
        float c1a[8], c1b[8];
#pragma unroll
        for (int k = 0; k < 8; ++k) {
            c1a[k] = 0.f; c1b[k] = 0.f;
            if (wi >= 0) {
                const float2 v = *(const float2*)
                    &CUR1[((size_t)wi * BATCH + b0 + k) * H_DIM + i0];
                c1a[k] = v.x; c1b[k] = v.y;
            }
        }

        // ---- mem1 update + pack spike bits (exact values) ------------------
        uint32_t mk = 0u;                       // bits 0..7 = se(h=2*lane), 8..15 = so
#pragma unroll
        for (int k = 0; k < 8; ++k) {
            m1a[k] = s1a[k] ? 0.f : __fadd_rn(__fmul_rn(0.9f, m1a[k]), c1a[k]);
            m1b[k] = s1b[k] ? 0.f : __fadd_rn(__fmul_rn(0.9f, m1b[k]), c1b[k]);
            s1a[k] = m1a[k] > 0.5f; s1b[k] = m1b[k] > 0.5f;
            mk |= (s1a[k] ? (1u << k) : 0u) | (s1b[k] ? (0x100u << k) : 0u);
        }

        // ---- dense cur2: ascending h; spikes via readlane, weights via LDS -
        float c2[8][2];
#pragma unroll
        for (int k = 0; k < 8; ++k) { c2[k][0] = 0.f; c2[k][1] = 0.f; }

#pragma unroll 4
        for (int j = 0; j < 64; ++j) {
            const float4 wv = lw[j * 64 + lane];                 // ds_read_b128
            const uint32_t M = (uint32_t)__builtin_amdgcn_readlane((int)mk, j);
#pragma unroll
            for (int k = 0; k < 8; ++k) {
                const float se = (M & (1u     << k)) ? 1.0f : 0.0f;  // uniform -> SGPR
                const float so = (M & (0x100u << k)) ? 1.0f : 0.0f;
                c2[k][0] = __fmaf_rn(se, wv.x, c2[k][0]);   // h = 2j,   i = i0
                c2[k][1] = __fmaf_rn(se, wv.y, c2[k][1]);   // h = 2j,   i = i0+1
                c2[k][0] = __fmaf_rn(so, wv.z, c2[k][0]);   // h = 2j+1, i = i0
                c2[k][1] = __fmaf_rn(so, wv.w, c2[k][1]);   // h = 2j+1, i = i0+1
            }
        }

        // ---- mem2 + spikes (exact) and linear output tail (relaxed) --------
#pragma unroll
        for (int k = 0; k < 8; ++k) {
            m2[k][0] = s2[k][0] ? 0.f : __fadd_rn(__fmul_rn(0.9f, m2[k][0]), c2[k][0]);
            m2[k][1] = s2[k][1] ? 0.f : __fadd_rn(__fmul_rn(0.9f, m2[k][1]), c2[k][1]);
            s2[k][0] = m2[k][0] > 0.5f; s2[k][1] = m2[k][1] > 0.5f;
            const float p0 = (s2[k][0] ? wex0 : 0.f) + (s2[k][1] ? wex1 : 0.f);
            const float p1 = (s2[k][0] ? wey0 : 0.f) + (s2[k][1] ? wey1 : 0.f);
            po0[k] = __fmaf_rn(0.9f, po0[k], p0);   // mem_out linear: order-safe
            po1[k] = __fmaf_rn(0.9f, po1[k], p1);
        }
    }

    // ---- reduce per-lane (2-i) partials over 64 lanes (128 i), write -------
#pragma unroll
    for (int k = 0; k < 8; ++k) {
        float r0 = po0[k], r1 = po1[k];
#pragma unroll
        for (int off = 32; off > 0; off >>= 1) {
            r0 += __shfl_xor(r0, off);
            r1 += __shfl_xor(r1, off);
        }
        if (lane == 0) {
            float2 o;
            o.x = __fmul_rn(r0, vx);
            o.y = __fmul_rn(r1, vy);
            *(float2*)(out + ((size_t)t * BATCH + b0 + k) * 2) = o;
        }
    }
}

// ---------------------------------------------------------------------------
extern "C" void kernel_launch(void* const* d_in, const int* in_sizes, int n_in,
                              void* d_out, int out_size, void* d_ws, size_t ws_size,
                              hipStream_t stream) {
    const float* x    = (const float*)d_in[0];   // (128,1024,96)
    const float* Win  = (const float*)d_in[1];   // (128,96)
    const float* Wh0  = (const float*)d_in[2];   // (128,128)
    const float* Wout = (const float*)d_in[3];   // (2,128)
    const float* vx   = (const float*)d_in[4];   // (1,)
    const float* vy   = (const float*)d_in[5];   // (1,)
    float* out  = (float*)d_out;                 // (128,1024,2)

    // workspace: CUR1 (85.5 MB) | WS (64.1 MB) | WinT (48 KB) | Wh0P (64 KB)
    float* CUR1 = (float*)d_ws;
    float* WS   = CUR1 + (size_t)NWIN * BATCH * H_DIM;
    float* WinT = WS   + (size_t)NWIN * BATCH * D_INPUT;
    float* Wh0P = WinT + (size_t)D_INPUT * H_DIM;

    kT_wint   <<<dim3(112),                  dim3(256), 0, stream>>>(Win, Wh0, WinT, Wh0P);
    kA0_winsum<<<dim3(BD / 256),             dim3(256), 0, stream>>>(x, WS);
    kA_wincur <<<dim3(NWIN, BATCH / 64),     dim3(256), 0, stream>>>(WS, WinT, CUR1);
    kB_snn    <<<dim3(BATCH / 128, T_STEPS), dim3(1024), 0, stream>>>(CUR1, Wh0P, Wout, vx, vy, out);
}